// Round 13
// baseline (110.306 us; speedup 1.0000x reference)
//
#include <hip/hip_runtime.h>
#include <hip/hip_bf16.h>

// Problem: B=2, T=2048, D=1024, H=16, DH=64
#define BB 2
#define TT 2048
#define DD 1024
#define HH 16
#define MM (BB*TT)        // 4096
#define N3 (3*DD)         // 3072
#define QKW 2048          // qkv2 row width (Q|K only)

typedef __attribute__((ext_vector_type(8))) short short8;
typedef __attribute__((ext_vector_type(4))) float f32x4;
typedef __attribute__((ext_vector_type(16))) float f32x16;

#define ZERO16 (f32x16){0,0,0,0,0,0,0,0,0,0,0,0,0,0,0,0}

#define GLDS16(g, l) __builtin_amdgcn_global_load_lds( \
    (const __attribute__((address_space(1))) void*)(g), \
    (__attribute__((address_space(3))) void*)(l), 16, 0, 0)

__device__ __forceinline__ unsigned short f2bf(float f) {
    union { float f; unsigned u; } v; v.f = f;
    unsigned r = v.u + 0x7FFFu + ((v.u >> 16) & 1u);
    return (unsigned short)(r >> 16);
}

__device__ __forceinline__ unsigned cvt_pk_bf16(float lo, float hi) {
    unsigned r;
    asm("v_cvt_pk_bf16_f32 %0, %1, %2" : "=v"(r) : "v"(lo), "v"(hi));
    return r;
}

__device__ __forceinline__ float fast_exp2(float x) {
    float r;
    asm("v_exp_f32 %0, %1" : "=v"(r) : "v"(x));
    return r;
}
__device__ __forceinline__ float fast_rcp(float x) {
    float r;
    asm("v_rcp_f32 %0, %1" : "=v"(r) : "v"(x));
    return r;
}

// ---------------- merged prep: Wqkv^T + Wproj^T + cast(x), one launch ----------------
__global__ void prep_kernel(const float* __restrict__ x,
                            const float* __restrict__ Wqkv,
                            const float* __restrict__ Wproj,
                            unsigned short* __restrict__ xb,
                            unsigned short* __restrict__ wqkvt,
                            unsigned short* __restrict__ wprojt) {
    __shared__ float tile[32][33];
    const int bid = blockIdx.x;
    const int tx = threadIdx.x, ty = threadIdx.y;
    if (bid < 4096) {
        const float* src;
        unsigned short* dst;
        int rows, cols, c0, r0;
        if (bid < 3072) {
            src = Wqkv; dst = wqkvt; rows = DD; cols = N3;
            c0 = (bid % 96) * 32; r0 = (bid / 96) * 32;
        } else {
            src = Wproj; dst = wprojt; rows = DD; cols = DD;
            int b2 = bid - 3072;
            c0 = (b2 & 31) * 32; r0 = (b2 >> 5) * 32;
        }
#pragma unroll
        for (int i = 0; i < 4; i++) {
            int r = ty + i * 8;
            tile[r][tx] = src[(size_t)(r0 + r) * cols + c0 + tx];
        }
        __syncthreads();
#pragma unroll
        for (int i = 0; i < 4; i++) {
            int r = ty + i * 8;
            dst[(size_t)(c0 + r) * rows + r0 + tx] = f2bf(tile[tx][r]);
        }
    } else {
        const int t = ty * 32 + tx;
        int i = (bid - 4096) * 256 + t;
#pragma unroll
        for (int k = 0; k < 2; k++, i += 262144) {
            const float4* s = reinterpret_cast<const float4*>(x) + (size_t)i * 2;
            float4 a = s[0], b = s[1];
            unsigned short r[8] = {f2bf(a.x), f2bf(a.y), f2bf(a.z), f2bf(a.w),
                                   f2bf(b.x), f2bf(b.y), f2bf(b.z), f2bf(b.w)};
            *reinterpret_cast<uint4*>(xb + (size_t)i * 8) = *reinterpret_cast<uint4*>(r);
        }
    }
}

// ============ 256x256 4-phase GEMM for QKV (M=4096, N=3072, K=1024) ============
// 512 threads = 8 waves (2M x 4N). 32-MFMA clusters, 8 barriers/iter (was 16).
// WAR-safe staging: STG_A(kt+2) in P2 (after last A(kt) ds_read drains at P1-exit).
__global__ __launch_bounds__(512, 2)
void gemm256_qkv(const unsigned short* __restrict__ A,
                 const unsigned short* __restrict__ Bt,
                 unsigned short* __restrict__ qkv2,
                 unsigned short* __restrict__ Vout,
                 float scale) {
    __shared__ unsigned short Al[2][2][128][64];
    __shared__ unsigned short Bl[2][2][128][64];

    const int id = blockIdx.y * 12 + blockIdx.x;          // nwg = 192, %8 == 0
    const int swzid = (id & 7) * 24 + (id >> 3);
    const int tm = (swzid / 12) * 256, tn = (swzid % 12) * 256;
    const int t = threadIdx.x, w = t >> 6, l = t & 63;
    const int wm = w >> 2, wn = w & 3, bh = wn >> 1;
    const int lo = l & 15, hi = l >> 4;
    const int srow = l >> 3;
    const int sg = (l & 7) ^ srow;

    f32x4 acc[8][4];
#pragma unroll
    for (int i = 0; i < 8; i++)
#pragma unroll
        for (int j = 0; j < 4; j++) acc[i][j] = (f32x4){0.f, 0.f, 0.f, 0.f};

    const unsigned short* Abase = A + (size_t)(tm + w * 16 + srow) * 1024 + sg * 8;
    const unsigned short* Bbase = Bt + (size_t)(tn + w * 16 + srow) * 1024 + sg * 8;

#define STG_A(KT, H) { \
    GLDS16(Abase + (size_t)(H) * 128 * 1024 + ((KT) & 15) * 64, &Al[(KT) & 1][H][w * 16][0]); \
    GLDS16(Abase + (size_t)(H) * 128 * 1024 + 8 * 1024 + ((KT) & 15) * 64, &Al[(KT) & 1][H][w * 16 + 8][0]); }
#define STG_B(KT, H) { \
    GLDS16(Bbase + (size_t)(H) * 128 * 1024 + ((KT) & 15) * 64, &Bl[(KT) & 1][H][w * 16][0]); \
    GLDS16(Bbase + (size_t)(H) * 128 * 1024 + 8 * 1024 + ((KT) & 15) * 64, &Bl[(KT) & 1][H][w * 16 + 8][0]); }

#define LOAD_A(AFR, KP, MH) { \
    const char* ab = (const char*)&Al[KP][wm][0][0]; \
    _Pragma("unroll") \
    for (int fi = 0; fi < 4; fi++) \
    _Pragma("unroll") \
    for (int ks = 0; ks < 2; ks++) \
        AFR[fi][ks] = *reinterpret_cast<const short8*>( \
            ab + ((MH) * 64 + fi * 16 + lo) * 128 + (((ks * 4 + hi) ^ (lo & 7)) << 4)); }
#define LOAD_B(BFR, KP, NH) { \
    const char* bb = (const char*)&Bl[KP][bh][0][0]; \
    _Pragma("unroll") \
    for (int fj = 0; fj < 2; fj++) \
    _Pragma("unroll") \
    for (int ks = 0; ks < 2; ks++) \
        BFR[fj][ks] = *reinterpret_cast<const short8*>( \
            bb + ((wn & 1) * 64 + (NH) * 32 + fj * 16 + lo) * 128 + (((ks * 4 + hi) ^ (lo & 7)) << 4)); }

#define MFMA16(MH, NH, AFR, BFR) { \
    _Pragma("unroll") \
    for (int ks = 0; ks < 2; ks++) \
    _Pragma("unroll") \
    for (int fi = 0; fi < 4; fi++) \
    _Pragma("unroll") \
    for (int fj = 0; fj < 2; fj++) \
        acc[(MH) * 4 + fi][(NH) * 2 + fj] = __builtin_amdgcn_mfma_f32_16x16x32_bf16( \
            AFR[fi][ks], BFR[fj][ks], acc[(MH) * 4 + fi][(NH) * 2 + fj], 0, 0, 0); }

#define BAR __builtin_amdgcn_s_barrier()
#define LGKM0 asm volatile("s_waitcnt lgkmcnt(0)")
#define P1 __builtin_amdgcn_s_setprio(1)
#define P0 __builtin_amdgcn_s_setprio(0)

    // prologue: kt0 fully + kt1's B; drain to 4 (leave B1's 4 in flight)
    STG_A(0, 0); STG_A(0, 1); STG_B(0, 0); STG_B(0, 1);
    STG_B(1, 0); STG_B(1, 1);
    asm volatile("s_waitcnt vmcnt(4)");
    BAR;

    for (int i = 0; i < 8; i++) {
        const int kt = 2 * i;
        short8 AF[4][2], BA[2][2], BF[2][2];
        // ---- P0: kt quadrants (0,0)+(0,1); stage A(kt+1) both halves ----
        LOAD_A(AF, 0, 0); LOAD_B(BA, 0, 0); LOAD_B(BF, 0, 1);
        STG_A(kt + 1, 0); STG_A(kt + 1, 1);
        BAR; LGKM0; P1; MFMA16(0, 0, AF, BA); MFMA16(0, 1, AF, BF); P0; BAR;
        // ---- P1: kt quadrants (1,1)+(1,0); stage B(kt+2); vmcnt(4) -> kt+1 ready ----
        LOAD_A(AF, 0, 1);
        STG_B(kt + 2, 0); STG_B(kt + 2, 1);
        BAR; LGKM0; P1; MFMA16(1, 1, AF, BF); MFMA16(1, 0, AF, BA); P0;
        asm volatile("s_waitcnt vmcnt(4)");
        BAR;
        // ---- P2: kt+1 quadrants (0,0)+(0,1); stage A(kt+2) both halves ----
        LOAD_A(AF, 1, 0); LOAD_B(BA, 1, 0); LOAD_B(BF, 1, 1);
        STG_A(kt + 2, 0); STG_A(kt + 2, 1);
        BAR; LGKM0; P1; MFMA16(0, 0, AF, BA); MFMA16(0, 1, AF, BF); P0; BAR;
        // ---- P3: kt+1 quadrants (1,1)+(1,0); stage B(kt+3); vmcnt(4) -> kt+2 ready ----
        LOAD_A(AF, 1, 1);
        STG_B(kt + 3, 0); STG_B(kt + 3, 1);
        BAR; LGKM0; P1; MFMA16(1, 1, AF, BF); MFMA16(1, 0, AF, BA); P0;
        asm volatile("s_waitcnt vmcnt(4)");
        BAR;
    }

    // ---- epilogue: Q|K -> qkv2 bf16 (Q scaled); V -> transposed Vout ----
#pragma unroll
    for (int i = 0; i < 8; i++)
#pragma unroll
        for (int j = 0; j < 4; j++) {
            const int col = tn + wn * 64 + j * 16 + lo;
            const int row0 = tm + wm * 128 + i * 16 + hi * 4;
            if (col < 2 * DD) {
                float s = (col < DD) ? scale : 1.0f;
#pragma unroll
                for (int r = 0; r < 4; r++)
                    qkv2[(size_t)(row0 + r) * QKW + col] = f2bf(acc[i][j][r] * s);
            } else {
                unsigned short pk[4];
#pragma unroll
                for (int r = 0; r < 4; r++) pk[r] = f2bf(acc[i][j][r]);
                *reinterpret_cast<uint2*>(&Vout[(size_t)(col - 2 * DD) * MM + row0]) =
                    *reinterpret_cast<uint2*>(pk);
            }
        }
#undef STG_A
#undef STG_B
#undef LOAD_A
#undef LOAD_B
#undef MFMA16
#undef BAR
#undef LGKM0
#undef P1
#undef P0
}

// ---------------- output projection GEMM: 128x64 tiles -> 512 blocks ----------------
__global__ __launch_bounds__(256)
void gemm_proj(const unsigned short* __restrict__ A,
               const unsigned short* __restrict__ Bt,
               float* __restrict__ Cout) {
    __shared__ unsigned short As[128][64];
    __shared__ unsigned short Bs[64][64];
    const int nbx = 16;
    const int id = blockIdx.y * nbx + blockIdx.x;
    const int cpx = 512 >> 3;
    const int swz = (id & 7) * cpx + (id >> 3);
    const int tm = (swz / nbx) * 128, tn = (swz % nbx) * 64;
    const int t = threadIdx.x;
    const int w = t >> 6, lane = t & 63, lo = lane & 15, hi = lane >> 4;
    const int wr = w >> 1, wc = w & 1;

    f32x4 acc[4][2];
#pragma unroll
    for (int i = 0; i < 4; i++)
#pragma unroll
        for (int j = 0; j < 2; j++) acc[i][j] = (f32x4){0.f, 0.f, 0.f, 0.f};

    const int sr8 = lane >> 3;
    const int scol = (lane & 7) * 8;
    const unsigned short* ga = &A[(size_t)(tm + w * 32 + sr8) * 1024 + scol];
    const unsigned short* gb = &Bt[(size_t)(tn + w * 16 + sr8) * 1024 + scol];

    for (int k0 = 0; k0 < 1024; k0 += 64) {
        __syncthreads();
#pragma unroll
        for (int i = 0; i < 4; i++)
            GLDS16(ga + (size_t)(i * 8) * 1024 + k0, &As[w * 32 + i * 8][0]);
#pragma unroll
        for (int i = 0; i < 2; i++)
            GLDS16(gb + (size_t)(i * 8) * 1024 + k0, &Bs[w * 16 + i * 8][0]);
        __syncthreads();

        short8 af[4][2], bf[2][2];
#pragma unroll
        for (int i = 0; i < 4; i++)
#pragma unroll
            for (int ks = 0; ks < 2; ks++)
                af[i][ks] = *reinterpret_cast<const short8*>(&As[wr * 64 + i * 16 + lo][ks * 32 + hi * 8]);
#pragma unroll
        for (int j = 0; j < 2; j++)
#pragma unroll
            for (int ks = 0; ks < 2; ks++)
                bf[j][ks] = *reinterpret_cast<const short8*>(&Bs[wc * 32 + j * 16 + lo][ks * 32 + hi * 8]);
#pragma unroll
        for (int ks = 0; ks < 2; ks++)
#pragma unroll
            for (int i = 0; i < 4; i++)
#pragma unroll
                for (int j = 0; j < 2; j++)
                    acc[i][j] = __builtin_amdgcn_mfma_f32_16x16x32_bf16(af[i][ks], bf[j][ks], acc[i][j], 0, 0, 0);
    }
#pragma unroll
    for (int i = 0; i < 4; i++)
#pragma unroll
        for (int j = 0; j < 2; j++) {
            const int col = tn + wc * 32 + j * 16 + lo;
            const int row0 = tm + wr * 64 + i * 16 + hi * 4;
#pragma unroll
            for (int r = 0; r < 4; r++)
                Cout[(size_t)(row0 + r) * DD + col] = acc[i][j][r];
        }
}

// ================ Flash attention: balanced 17-step schedule, 4-slot LDS ring ================
struct AttnState {
    f32x16 o0, o1, lD;
};

__device__ __forceinline__ void attn_full_tile(
        const char* kbase, const char* vbase, const short8* bq, short8 ones1,
        AttnState& st, int sw4, int ql, int hi8, bool domask, int kvb, int qg) {
    short8 ak0[4], ak1[4];
#pragma unroll
    for (int ks = 0; ks < 4; ks++) {
        ak0[ks] = *reinterpret_cast<const short8*>(kbase + ql * 128 + (((ks * 2 + hi8) << 4) ^ sw4));
        ak1[ks] = *reinterpret_cast<const short8*>(kbase + (32 + ql) * 128 + (((ks * 2 + hi8) << 4) ^ sw4));
    }
    f32x16 sa0 = ZERO16, sa1 = ZERO16;
    __builtin_amdgcn_s_setprio(1);
#pragma unroll
    for (int ks = 0; ks < 4; ks++) {
        sa0 = __builtin_amdgcn_mfma_f32_32x32x16_bf16(ak0[ks], bq[ks], sa0, 0, 0, 0);
        sa1 = __builtin_amdgcn_mfma_f32_32x32x16_bf16(ak1[ks], bq[ks], sa1, 0, 0, 0);
    }
    __builtin_amdgcn_s_setprio(0);
    if (domask) {
#pragma unroll
        for (int r = 0; r < 16; r++) {
            int crow = (r & 3) + 8 * (r >> 2) + 4 * hi8;
            if (kvb + crow > qg) sa0[r] = -1e30f;
            if (kvb + 32 + crow > qg) sa1[r] = -1e30f;
        }
    }
#pragma unroll
    for (int r = 0; r < 16; r++) sa0[r] = fast_exp2(sa0[r]);
#pragma unroll
    for (int r = 0; r < 16; r++) sa1[r] = fast_exp2(sa1[r]);

    unsigned a01 = cvt_pk_bf16(sa0[0], sa0[1]),  a23 = cvt_pk_bf16(sa0[2], sa0[3]);
    unsigned a45 = cvt_pk_bf16(sa0[4], sa0[5]),  a67 = cvt_pk_bf16(sa0[6], sa0[7]);
    asm("v_permlane32_swap_b32 %0, %1" : "+v"(a01), "+v"(a45));
    asm("v_permlane32_swap_b32 %0, %1" : "+v"(a23), "+v"(a67));
    unsigned b01 = cvt_pk_bf16(sa0[8], sa0[9]),  b23 = cvt_pk_bf16(sa0[10], sa0[11]);
    unsigned b45 = cvt_pk_bf16(sa0[12], sa0[13]), b67 = cvt_pk_bf16(sa0[14], sa0[15]);
    asm("v_permlane32_swap_b32 %0, %1" : "+v"(b01), "+v"(b45));
    asm("v_permlane32_swap_b32 %0, %1" : "+v"(b23), "+v"(b67));
    unsigned c01 = cvt_pk_bf16(sa1[0], sa1[1]),  c23 = cvt_pk_bf16(sa1[2], sa1[3]);
    unsigned c45 = cvt_pk_bf16(sa1[4], sa1[5]),  c67 = cvt_pk_bf16(sa1[6], sa1[7]);
    asm("v_permlane32_swap_b32 %0, %1" : "+v"(c01), "+v"(c45));
    asm("v_permlane32_swap_b32 %0, %1" : "+v"(c23), "+v"(c67));
    unsigned d01 = cvt_pk_bf16(sa1[8], sa1[9]),  d23 = cvt_pk_bf16(sa1[10], sa1[11]);
    unsigned d45 = cvt_pk_bf16(sa1[12], sa1[13]), d67 = cvt_pk_bf16(sa1[14], sa1[15]);
    asm("v_permlane32_swap_b32 %0, %1" : "+v"(d01), "+v"(d45));
    asm("v_permlane32_swap_b32 %0, %1" : "+v"(d23), "+v"(d67));
    union { unsigned u[4]; short8 s; } f0s0, f1s0, f0s1, f1s1;
    f0s0.u[0] = a01; f0s0.u[1] = a23; f0s0.u[2] = a45; f0s0.u[3] = a67;
    f1s0.u[0] = b01; f1s0.u[1] = b23; f1s0.u[2] = b45; f1s0.u[3] = b67;
    f0s1.u[0] = c01; f0s1.u[1] = c23; f0s1.u[2] = c45; f0s1.u[3] = c67;
    f1s1.u[0] = d01; f1s1.u[1] = d23; f1s1.u[2] = d45; f1s1.u[3] = d67;

    short8 bv00 = *reinterpret_cast<const short8*>(vbase + ql * 128 + (((0 + hi8) << 4) ^ sw4));
    short8 bv01 = *reinterpret_cast<const short8*>(vbase + ql * 128 + (((2 + hi8) << 4) ^ sw4));
    short8 bv02 = *reinterpret_cast<const short8*>(vbase + ql * 128 + (((4 + hi8) << 4) ^ sw4));
    short8 bv03 = *reinterpret_cast<const short8*>(vbase + ql * 128 + (((6 + hi8) << 4) ^ sw4));
    short8 bv10 = *reinterpret_cast<const short8*>(vbase + (32 + ql) * 128 + (((0 + hi8) << 4) ^ sw4));
    short8 bv11 = *reinterpret_cast<const short8*>(vbase + (32 + ql) * 128 + (((2 + hi8) << 4) ^ sw4));
    short8 bv12 = *reinterpret_cast<const short8*>(vbase + (32 + ql) * 128 + (((4 + hi8) << 4) ^ sw4));
    short8 bv13 = *reinterpret_cast<const short8*>(vbase + (32 + ql) * 128 + (((6 + hi8) << 4) ^ sw4));
    __builtin_amdgcn_s_setprio(1);
    st.lD = __builtin_amdgcn_mfma_f32_32x32x16_bf16(f0s0.s, ones1, st.lD, 0, 0, 0);
    st.lD = __builtin_amdgcn_mfma_f32_32x32x16_bf16(f1s0.s, ones1, st.lD, 0, 0, 0);
    st.lD = __builtin_amdgcn_mfma_f32_32x32x16_bf16(f0s1.s, ones1, st.lD, 0, 0, 0);
    st.lD = __builtin_amdgcn_mfma_f32_32x32x16_bf16(f1s1.s, ones1, st.lD, 0, 0, 0);
    st.o0 = __builtin_amdgcn_mfma_f32_32x32x16_bf16(f0s0.s, bv00, st.o0, 0, 0, 0);
    st.o1 = __builtin_amdgcn_mfma_f32_32x32x16_bf16(f0s0.s, bv10, st.o1, 0, 0, 0);
    st.o0 = __builtin_amdgcn_mfma_f32_32x32x16_bf16(f1s0.s, bv01, st.o0, 0, 0, 0);
    st.o1 = __builtin_amdgcn_mfma_f32_32x32x16_bf16(f1s0.s, bv11, st.o1, 0, 0, 0);
    st.o0 = __builtin_amdgcn_mfma_f32_32x32x16_bf16(f0s1.s, bv02, st.o0, 0, 0, 0);
    st.o1 = __builtin_amdgcn_mfma_f32_32x32x16_bf16(f0s1.s, bv12, st.o1, 0, 0, 0);
    st.o0 = __builtin_amdgcn_mfma_f32_32x32x16_bf16(f1s1.s, bv03, st.o0, 0, 0, 0);
    st.o1 = __builtin_amdgcn_mfma_f32_32x32x16_bf16(f1s1.s, bv13, st.o1, 0, 0, 0);
    __builtin_amdgcn_s_setprio(0);
}

__device__ __forceinline__ void attn_half_tile(
        const char* kbase, const char* vbase, const short8* bq, short8 ones1,
        AttnState& st, int sw4, int ql, int hi8, int sub, int kvb, int qg) {
    short8 ak[4];
#pragma unroll
    for (int ks = 0; ks < 4; ks++)
        ak[ks] = *reinterpret_cast<const short8*>(
            kbase + (sub * 32 + ql) * 128 + (((ks * 2 + hi8) << 4) ^ sw4));
    f32x16 sa = ZERO16;
#pragma unroll
    for (int ks = 0; ks < 4; ks++)
        sa = __builtin_amdgcn_mfma_f32_32x32x16_bf16(ak[ks], bq[ks], sa, 0, 0, 0);

#pragma unroll
    for (int r = 0; r < 16; r++) {
        int crow = (r & 3) + 8 * (r >> 2) + 4 * hi8;
        if (kvb + sub * 32 + crow > qg) sa[r] = -1e30f;
    }
#pragma unroll
    for (int r = 0; r < 16; r++) sa[r] = fast_exp2(sa[r]);

    unsigned a01 = cvt_pk_bf16(sa[0], sa[1]),  a23 = cvt_pk_bf16(sa[2], sa[3]);
    unsigned a45 = cvt_pk_bf16(sa[4], sa[5]),  a67 = cvt_pk_bf16(sa[6], sa[7]);
    asm("v_permlane32_swap_b32 %0, %1" : "+v"(a01), "+v"(a45));
    asm("v_permlane32_swap_b32 %0, %1" : "+v"(a23), "+v"(a67));
    unsigned b01 = cvt_pk_bf16(sa[8], sa[9]),  b23 = cvt_pk_bf16(sa[10], sa[11]);
    unsigned b45 = cvt_pk_bf16(sa[12], sa[13]), b67 = cvt_pk_bf16(sa[14], sa[15]);
    asm("v_permlane32_swap_b32 %0, %1" : "+v"(b01), "+v"(b45));
    asm("v_permlane32_swap_b32 %0, %1" : "+v"(b23), "+v"(b67));
    union { unsigned u[4]; short8 s; } f0, f1;
    f0.u[0] = a01; f0.u[1] = a23; f0.u[2] = a45; f0.u[3] = a67;
    f1.u[0] = b01; f1.u[1] = b23; f1.u[2] = b45; f1.u[3] = b67;

    st.lD = __builtin_amdgcn_mfma_f32_32x32x16_bf16(f0.s, ones1, st.lD, 0, 0, 0);
    st.lD = __builtin_amdgcn_mfma_f32_32x32x16_bf16(f1.s, ones1, st.lD, 0, 0, 0);

    short8 bv00 = *reinterpret_cast<const short8*>(vbase + ql * 128 + (((sub * 4 + 0 + hi8) << 4) ^ sw4));
    short8 bv01 = *reinterpret_cast<const short8*>(vbase + ql * 128 + (((sub * 4 + 2 + hi8) << 4) ^ sw4));
    short8 bv10 = *reinterpret_cast<const short8*>(vbase + (32 + ql) * 128 + (((sub * 4 + 0 + hi8) << 4) ^ sw4));
    short8 bv11 = *reinterpret_cast<const short8*>(vbase + (32 + ql) * 128 + (((sub * 4 + 2 + hi8) << 4) ^ sw4));
    st.o0 = __builtin_amdgcn_mfma_f32_32x32x16_bf16(f0.s, bv00, st.o0, 0, 0, 0);
    st.o1 = __builtin_amdgcn_mfma_f32_32x32x16_bf16(f0.s, bv10, st.o1, 0, 0, 0);
    st.o0 = __builtin_amdgcn_mfma_f32_32x32x16_bf16(f1.s, bv01, st.o0, 0, 0, 0);
    st.o1 = __builtin_amdgcn_mfma_f32_32x32x16_bf16(f1.s, bv11, st.o1, 0, 0, 0);
}

__global__ __launch_bounds__(256)
void attn_kernel(const unsigned short* __restrict__ qkv2,   // [B*T][2048] Q|K bf16
                 const unsigned short* __restrict__ vtg,    // [1024][B*T]  V^T bf16
                 unsigned short* __restrict__ outp) {
    __shared__ unsigned short Ks[4][64][64];   // 4-slot ring, XOR-swizzled rows
    __shared__ unsigned short Vt[4][64][64];

    const int b = blockIdx.z, h = blockIdx.x, p = blockIdx.y;
    const int qcl = p, qch = 31 - p;
    const int L = p + 1, Hn = 32 - p;
    const int NSTEP = 17;
    const int t = threadIdx.x;
    const int w = t >> 6, l = t & 63, ql = l & 31, hi8 = l >> 5;
    const int pr = w >> 1, rg = w & 1;
    const int q0h = qch * 64 + rg * 32;
    const int q0l = qcl * 64 + rg * 32;
    const int q0p = pr ? q0l : q0h;
    const unsigned short* base2 = qkv2 + (size_t)b * TT * QKW;

    short8 bq[4];
#pragma unroll
    for (int ks = 0; ks < 4; ks++)
        bq[ks] = *reinterpret_cast<const short8*>(
            &base2[(size_t)(q0p + ql) * QKW + h * 64 + ks * 16 + hi8 * 8]);

    AttnState st;
    st.o0 = ZERO16; st.o1 = ZERO16; st.lD = ZERO16;

    short8 ones1;
#pragma unroll
    for (int j = 0; j < 8; j++) ones1[j] = (short)0x3F80;

    const int krow = l >> 3;
    const int kc8 = (l & 7) ^ krow;
    const unsigned short* gk = &base2[(size_t)(w * 8 + krow) * QKW + DD + h * 64 + kc8 * 8];
    const unsigned short* gv = &vtg[(size_t)(h * 64 + w * 8 + krow) * MM + b * TT + kc8 * 8];

#define STAGE(TI) { \
    const int _s = (TI) & 3; \
    const size_t _kb = (size_t)(TI) * 64; \
    GLDS16(gk + _kb * QKW, &Ks[_s][w * 8][0]); \
    GLDS16(gk + (_kb + 32) * QKW, &Ks[_s][32 + w * 8][0]); \
    GLDS16(gv + _kb, &Vt[_s][w * 8][0]); \
    GLDS16(gv + (size_t)32 * MM + _kb, &Vt[_s][32 + w * 8][0]); }

#define WRITE_OUT(Q0) { \
    _Pragma("unroll") \
    for (int r = 0; r < 16; r++) { \
        int src = (r & 3) + 8 * (r >> 2) + 4 * hi8; \
        float inv = fast_rcp(st.lD[r]); \
        size_t off = (size_t)(b * TT + (Q0) + src) * DD + h * 64 + ql; \
        outp[off] = f2bf(st.o0[r] * inv); \
        outp[off + 32] = f2bf(st.o1[r] * inv); \
    } }

    STAGE(0);
    int nIss = 1;
    __syncthreads();

    const int sw4 = (ql & 7) << 4;
    for (int s = 0; s < NSTEP; s++) {
        // issue stages needed by step s+1
        {
            const int sn = s + 1;
            int lastN;
            if (sn < L) lastN = sn;
            else if (sn < NSTEP - 1) lastN = L + 2 * (sn - L) + 1;
            else if (sn == NSTEP - 1) lastN = Hn - 1;
            else lastN = -1;
            while (nIss <= lastN) { STAGE(nIss); nIss++; }
        }

        if (s == L && pr == 1) {
            WRITE_OUT(q0l);
            st.o0 = ZERO16; st.o1 = ZERO16; st.lD = ZERO16;
#pragma unroll
            for (int ks = 0; ks < 4; ks++)
                bq[ks] = *reinterpret_cast<const short8*>(
                    &base2[(size_t)(q0h + ql) * QKW + h * 64 + ks * 16 + hi8 * 8]);
        }

        if (s < L) {
            const int tile = s;
            const char* kbase = (const char*)&Ks[tile & 3][0][0];
            const char* vbase = (const char*)&Vt[tile & 3][0][0];
            const bool domask = (pr == 1) && (s == L - 1);
            attn_full_tile(kbase, vbase, bq, ones1, st, sw4, ql, hi8,
                           domask, tile * 64, q0p + ql);
        } else if (s < NSTEP - 1) {
            const int tile = L + 2 * (s - L) + pr;
            const char* kbase = (const char*)&Ks[tile & 3][0][0];
            const char* vbase = (const char*)&Vt[tile & 3][0][0];
            attn_full_tile(kbase, vbase, bq, ones1, st, sw4, ql, hi8,
                           false, 0, 0);
        } else {
            const int tile = Hn - 1;
            const char* kbase = (const char*)&Ks[tile & 3][0][0];
            const char* vbase = (const char*)&Vt[tile & 3][0][0];
            attn_half_tile(kbase, vbase, bq, ones1, st, sw4, ql, hi8,
                           pr, tile * 64, q0h + ql);
        }
        __syncthreads();
    }

    // merge pair-1 heavy partials into pair 0
    float* xf = (float*)&Ks[0][0][0];
    float* xl = (float*)&Vt[0][0][0];
    const int tid128 = (w & 1) * 64 + l;
    if (pr == 1) {
#pragma unroll
        for (int r = 0; r < 16; r++) {
            xf[r * 128 + tid128] = st.o0[r];
            xf[(16 + r) * 128 + tid128] = st.o1[r];
            xl[r * 128 + tid128] = st.lD[r];
        }
    }
    __syncthreads();
    if (pr == 0) {
#pragma unroll
        for (int r = 0; r < 16; r++) {
            st.o0[r] += xf[r * 128 + tid128];
            st.o1[r] += xf[(16 + r) * 128 + tid128];
            st.lD[r] += xl[r * 128 + tid128];
        }
        WRITE_OUT(q0h);
    }
#undef STAGE
#undef WRITE_OUT
}

extern "C" void kernel_launch(void* const* d_in, const int* in_sizes, int n_in,
                              void* d_out, int out_size, void* d_ws, size_t ws_size,
                              hipStream_t stream) {
    const float* x     = (const float*)d_in[0];   // [4096][1024]
    const float* Wqkv  = (const float*)d_in[1];   // [1024][3072]
    const float* Wproj = (const float*)d_in[2];   // [1024][1024]
    float* out = (float*)d_out;                    // [4096][1024] fp32

    unsigned short* xb     = (unsigned short*)d_ws;            // 4096*1024
    unsigned short* wqkvt  = xb + (size_t)MM * DD;             // 3072*1024
    unsigned short* wprojt = wqkvt + (size_t)N3 * DD;          // 1024*1024
    unsigned short* qkv2   = wprojt + (size_t)DD * DD;         // 4096*2048 (Q|K)
    unsigned short* vtg    = qkv2 + (size_t)MM * QKW;          // 1024*4096 (V^T)
    unsigned short* attout = vtg + (size_t)DD * MM;            // 4096*1024
    size_t need = ((size_t)MM * DD + (size_t)N3 * DD + (size_t)DD * DD +
                   (size_t)MM * QKW + (size_t)DD * MM + (size_t)MM * DD) * 2;
    if (ws_size < need) return;

    const float sc = 0.125f * 1.44269504088896f;   // 1/sqrt(64) * log2(e), folded into Q

    prep_kernel<<<5120, dim3(32, 8), 0, stream>>>(x, Wqkv, Wproj, xb, wqkvt, wprojt);

    gemm256_qkv<<<dim3(12, 16), 512, 0, stream>>>(xb, wqkvt, qkv2, vtg, sc);

    attn_kernel<<<dim3(HH, 16, BB), 256, 0, stream>>>(qkv2, vtg, attout);

    gemm_proj<<<dim3(16, 32), 256, 0, stream>>>(attout, wprojt, out);
}

// Round 14
// 100.816 us; speedup vs baseline: 1.0941x; 1.0941x over previous
//
#include <hip/hip_runtime.h>
#include <hip/hip_bf16.h>

// Problem: B=2, T=2048, D=1024, H=16, DH=64
#define BB 2
#define TT 2048
#define DD 1024
#define HH 16
#define MM (BB*TT)        // 4096
#define N3 (3*DD)         // 3072
#define QKW 2048          // qkv2 row width (Q|K only)

typedef __attribute__((ext_vector_type(8))) short short8;
typedef __attribute__((ext_vector_type(4))) float f32x4;
typedef __attribute__((ext_vector_type(16))) float f32x16;

#define ZERO16 (f32x16){0,0,0,0,0,0,0,0,0,0,0,0,0,0,0,0}

#define GLDS16(g, l) __builtin_amdgcn_global_load_lds( \
    (const __attribute__((address_space(1))) void*)(g), \
    (__attribute__((address_space(3))) void*)(l), 16, 0, 0)

__device__ __forceinline__ unsigned short f2bf(float f) {
    union { float f; unsigned u; } v; v.f = f;
    unsigned r = v.u + 0x7FFFu + ((v.u >> 16) & 1u);
    return (unsigned short)(r >> 16);
}

__device__ __forceinline__ unsigned cvt_pk_bf16(float lo, float hi) {
    unsigned r;
    asm("v_cvt_pk_bf16_f32 %0, %1, %2" : "=v"(r) : "v"(lo), "v"(hi));
    return r;
}

__device__ __forceinline__ float fast_exp2(float x) {
    float r;
    asm("v_exp_f32 %0, %1" : "=v"(r) : "v"(x));
    return r;
}
__device__ __forceinline__ float fast_rcp(float x) {
    float r;
    asm("v_rcp_f32 %0, %1" : "=v"(r) : "v"(x));
    return r;
}

// ---------------- merged prep: Wqkv^T + Wproj^T + cast(x), one launch ----------------
__global__ void prep_kernel(const float* __restrict__ x,
                            const float* __restrict__ Wqkv,
                            const float* __restrict__ Wproj,
                            unsigned short* __restrict__ xb,
                            unsigned short* __restrict__ wqkvt,
                            unsigned short* __restrict__ wprojt) {
    __shared__ float tile[32][33];
    const int bid = blockIdx.x;
    const int tx = threadIdx.x, ty = threadIdx.y;
    if (bid < 4096) {
        const float* src;
        unsigned short* dst;
        int rows, cols, c0, r0;
        if (bid < 3072) {
            src = Wqkv; dst = wqkvt; rows = DD; cols = N3;
            c0 = (bid % 96) * 32; r0 = (bid / 96) * 32;
        } else {
            src = Wproj; dst = wprojt; rows = DD; cols = DD;
            int b2 = bid - 3072;
            c0 = (b2 & 31) * 32; r0 = (b2 >> 5) * 32;
        }
#pragma unroll
        for (int i = 0; i < 4; i++) {
            int r = ty + i * 8;
            tile[r][tx] = src[(size_t)(r0 + r) * cols + c0 + tx];
        }
        __syncthreads();
#pragma unroll
        for (int i = 0; i < 4; i++) {
            int r = ty + i * 8;
            dst[(size_t)(c0 + r) * rows + r0 + tx] = f2bf(tile[tx][r]);
        }
    } else {
        const int t = ty * 32 + tx;
        int i = (bid - 4096) * 256 + t;
#pragma unroll
        for (int k = 0; k < 2; k++, i += 262144) {
            const float4* s = reinterpret_cast<const float4*>(x) + (size_t)i * 2;
            float4 a = s[0], b = s[1];
            unsigned short r[8] = {f2bf(a.x), f2bf(a.y), f2bf(a.z), f2bf(a.w),
                                   f2bf(b.x), f2bf(b.y), f2bf(b.z), f2bf(b.w)};
            *reinterpret_cast<uint4*>(xb + (size_t)i * 8) = *reinterpret_cast<uint4*>(r);
        }
    }
}

// ============ 256x192 4-phase GEMM for QKV (M=4096, N=3072, K=1024) ============
// grid 16x16 = 256 blocks = exactly 1 per CU (was 192 -> 64 idle CUs).
// 512 threads = 8 waves (2M x 4N); per wave 128x48 (acc[8][3]); 24-MFMA clusters.
// Counted vmcnt(3): B-stage = 3 GLDS/wave; ledger: 10 outstanding -> drain to 3.
__global__ __launch_bounds__(512, 2)
void gemm256_qkv(const unsigned short* __restrict__ A,
                 const unsigned short* __restrict__ Bt,
                 unsigned short* __restrict__ qkv2,
                 unsigned short* __restrict__ Vout,
                 float scale) {
    __shared__ unsigned short Al[2][2][128][64];   // [parity][M-half][row][col] 64 KB
    __shared__ unsigned short Bl[2][192][64];      // [parity][row][col]         48 KB

    const int id = blockIdx.y * 16 + blockIdx.x;          // nwg = 256, %8 == 0
    const int swzid = (id & 7) * 32 + (id >> 3);          // bijective XCD swizzle
    const int tm = (swzid >> 4) * 256, tn = (swzid & 15) * 192;
    const int t = threadIdx.x, w = t >> 6, l = t & 63;
    const int wm = w >> 2, wn = w & 3;
    const int lo = l & 15, hi = l >> 4;
    const int srow = l >> 3;
    const int sg = (l & 7) ^ srow;

    f32x4 acc[8][3];
#pragma unroll
    for (int i = 0; i < 8; i++)
#pragma unroll
        for (int j = 0; j < 3; j++) acc[i][j] = (f32x4){0.f, 0.f, 0.f, 0.f};

    const unsigned short* Abase = A + (size_t)(tm + w * 16 + srow) * 1024 + sg * 8;
    const unsigned short* Bbase = Bt + (size_t)(tn + w * 24 + srow) * 1024 + sg * 8;

#define STG_A(KT, H) { \
    GLDS16(Abase + (size_t)(H) * 128 * 1024 + ((KT) & 15) * 64, &Al[(KT) & 1][H][w * 16][0]); \
    GLDS16(Abase + (size_t)(H) * 128 * 1024 + 8 * 1024 + ((KT) & 15) * 64, &Al[(KT) & 1][H][w * 16 + 8][0]); }
#define STG_B(KT) { \
    GLDS16(Bbase + ((KT) & 15) * 64, &Bl[(KT) & 1][w * 24][0]); \
    GLDS16(Bbase + (size_t)8 * 1024 + ((KT) & 15) * 64, &Bl[(KT) & 1][w * 24 + 8][0]); \
    GLDS16(Bbase + (size_t)16 * 1024 + ((KT) & 15) * 64, &Bl[(KT) & 1][w * 24 + 16][0]); }

#define LOAD_A(AFR, KP, MH) { \
    const char* ab = (const char*)&Al[KP][wm][0][0]; \
    _Pragma("unroll") \
    for (int fi = 0; fi < 4; fi++) \
    _Pragma("unroll") \
    for (int ks = 0; ks < 2; ks++) \
        AFR[fi][ks] = *reinterpret_cast<const short8*>( \
            ab + ((MH) * 64 + fi * 16 + lo) * 128 + (((ks * 4 + hi) ^ (lo & 7)) << 4)); }
#define LOAD_B(BFR, KP) { \
    const char* bb = (const char*)&Bl[KP][0][0]; \
    _Pragma("unroll") \
    for (int fj = 0; fj < 3; fj++) \
    _Pragma("unroll") \
    for (int ks = 0; ks < 2; ks++) \
        BFR[fj][ks] = *reinterpret_cast<const short8*>( \
            bb + (wn * 48 + fj * 16 + lo) * 128 + (((ks * 4 + hi) ^ (lo & 7)) << 4)); }

#define MFMA24(MH, AFR, BFR) { \
    _Pragma("unroll") \
    for (int ks = 0; ks < 2; ks++) \
    _Pragma("unroll") \
    for (int fi = 0; fi < 4; fi++) \
    _Pragma("unroll") \
    for (int fj = 0; fj < 3; fj++) \
        acc[(MH) * 4 + fi][fj] = __builtin_amdgcn_mfma_f32_16x16x32_bf16( \
            AFR[fi][ks], BFR[fj][ks], acc[(MH) * 4 + fi][fj], 0, 0, 0); }

#define BAR __builtin_amdgcn_s_barrier()
#define LGKM0 asm volatile("s_waitcnt lgkmcnt(0)")
#define SP1 __builtin_amdgcn_s_setprio(1)
#define SP0 __builtin_amdgcn_s_setprio(0)

    // prologue: A(0), B(0), B(1) in flight (10/wave); drain to B(1)'s 3
    STG_A(0, 0); STG_A(0, 1); STG_B(0); STG_B(1);
    asm volatile("s_waitcnt vmcnt(3)");
    BAR;

    for (int i = 0; i < 8; i++) {
        const int kt = 2 * i;
        short8 AF[4][2], BF[3][2];
        // ---- P0: kt M-half 0; stage A(kt+1) both halves ----
        LOAD_A(AF, 0, 0); LOAD_B(BF, 0);
        STG_A(kt + 1, 0); STG_A(kt + 1, 1);
        BAR; LGKM0; SP1; MFMA24(0, AF, BF); SP0; BAR;
        // ---- P1: kt M-half 1; stage B(kt+2); vmcnt(3) -> kt+1 ready ----
        LOAD_A(AF, 0, 1);
        STG_B(kt + 2);
        BAR; LGKM0; SP1; MFMA24(1, AF, BF); SP0;
        asm volatile("s_waitcnt vmcnt(3)");
        BAR;
        // ---- P2: kt+1 M-half 0; stage A(kt+2) both halves ----
        LOAD_A(AF, 1, 0); LOAD_B(BF, 1);
        STG_A(kt + 2, 0); STG_A(kt + 2, 1);
        BAR; LGKM0; SP1; MFMA24(0, AF, BF); SP0; BAR;
        // ---- P3: kt+1 M-half 1; stage B(kt+3); vmcnt(3) -> kt+2 ready ----
        LOAD_A(AF, 1, 1);
        STG_B(kt + 3);
        BAR; LGKM0; SP1; MFMA24(1, AF, BF); SP0;
        asm volatile("s_waitcnt vmcnt(3)");
        BAR;
    }

    // ---- epilogue: Q|K -> qkv2 bf16 (Q scaled); V -> transposed Vout ----
#pragma unroll
    for (int i = 0; i < 8; i++)
#pragma unroll
        for (int j = 0; j < 3; j++) {
            const int col = tn + wn * 48 + j * 16 + lo;
            const int row0 = tm + wm * 128 + i * 16 + hi * 4;
            if (col < 2 * DD) {
                float s = (col < DD) ? scale : 1.0f;
#pragma unroll
                for (int r = 0; r < 4; r++)
                    qkv2[(size_t)(row0 + r) * QKW + col] = f2bf(acc[i][j][r] * s);
            } else {
                unsigned short pk[4];
#pragma unroll
                for (int r = 0; r < 4; r++) pk[r] = f2bf(acc[i][j][r]);
                *reinterpret_cast<uint2*>(&Vout[(size_t)(col - 2 * DD) * MM + row0]) =
                    *reinterpret_cast<uint2*>(pk);
            }
        }
#undef STG_A
#undef STG_B
#undef LOAD_A
#undef LOAD_B
#undef MFMA24
#undef BAR
#undef LGKM0
#undef SP1
#undef SP0
}

// ---------------- output projection GEMM: 128x64 tiles -> 512 blocks ----------------
__global__ __launch_bounds__(256)
void gemm_proj(const unsigned short* __restrict__ A,
               const unsigned short* __restrict__ Bt,
               float* __restrict__ Cout) {
    __shared__ unsigned short As[128][64];
    __shared__ unsigned short Bs[64][64];
    const int nbx = 16;
    const int id = blockIdx.y * nbx + blockIdx.x;
    const int cpx = 512 >> 3;
    const int swz = (id & 7) * cpx + (id >> 3);
    const int tm = (swz / nbx) * 128, tn = (swz % nbx) * 64;
    const int t = threadIdx.x;
    const int w = t >> 6, lane = t & 63, lo = lane & 15, hi = lane >> 4;
    const int wr = w >> 1, wc = w & 1;

    f32x4 acc[4][2];
#pragma unroll
    for (int i = 0; i < 4; i++)
#pragma unroll
        for (int j = 0; j < 2; j++) acc[i][j] = (f32x4){0.f, 0.f, 0.f, 0.f};

    const int sr8 = lane >> 3;
    const int scol = (lane & 7) * 8;
    const unsigned short* ga = &A[(size_t)(tm + w * 32 + sr8) * 1024 + scol];
    const unsigned short* gb = &Bt[(size_t)(tn + w * 16 + sr8) * 1024 + scol];

    for (int k0 = 0; k0 < 1024; k0 += 64) {
        __syncthreads();
#pragma unroll
        for (int i = 0; i < 4; i++)
            GLDS16(ga + (size_t)(i * 8) * 1024 + k0, &As[w * 32 + i * 8][0]);
#pragma unroll
        for (int i = 0; i < 2; i++)
            GLDS16(gb + (size_t)(i * 8) * 1024 + k0, &Bs[w * 16 + i * 8][0]);
        __syncthreads();

        short8 af[4][2], bf[2][2];
#pragma unroll
        for (int i = 0; i < 4; i++)
#pragma unroll
            for (int ks = 0; ks < 2; ks++)
                af[i][ks] = *reinterpret_cast<const short8*>(&As[wr * 64 + i * 16 + lo][ks * 32 + hi * 8]);
#pragma unroll
        for (int j = 0; j < 2; j++)
#pragma unroll
            for (int ks = 0; ks < 2; ks++)
                bf[j][ks] = *reinterpret_cast<const short8*>(&Bs[wc * 32 + j * 16 + lo][ks * 32 + hi * 8]);
#pragma unroll
        for (int ks = 0; ks < 2; ks++)
#pragma unroll
            for (int i = 0; i < 4; i++)
#pragma unroll
                for (int j = 0; j < 2; j++)
                    acc[i][j] = __builtin_amdgcn_mfma_f32_16x16x32_bf16(af[i][ks], bf[j][ks], acc[i][j], 0, 0, 0);
    }
#pragma unroll
    for (int i = 0; i < 4; i++)
#pragma unroll
        for (int j = 0; j < 2; j++) {
            const int col = tn + wc * 32 + j * 16 + lo;
            const int row0 = tm + wr * 64 + i * 16 + hi * 4;
#pragma unroll
            for (int r = 0; r < 4; r++)
                Cout[(size_t)(row0 + r) * DD + col] = acc[i][j][r];
        }
}

// ================ Flash attention: balanced 17-step schedule, 4-slot LDS ring ================
struct AttnState {
    f32x16 o0, o1, lD;
};

__device__ __forceinline__ void attn_full_tile(
        const char* kbase, const char* vbase, const short8* bq, short8 ones1,
        AttnState& st, int sw4, int ql, int hi8, bool domask, int kvb, int qg) {
    short8 ak0[4], ak1[4];
#pragma unroll
    for (int ks = 0; ks < 4; ks++) {
        ak0[ks] = *reinterpret_cast<const short8*>(kbase + ql * 128 + (((ks * 2 + hi8) << 4) ^ sw4));
        ak1[ks] = *reinterpret_cast<const short8*>(kbase + (32 + ql) * 128 + (((ks * 2 + hi8) << 4) ^ sw4));
    }
    f32x16 sa0 = ZERO16, sa1 = ZERO16;
    __builtin_amdgcn_s_setprio(1);
#pragma unroll
    for (int ks = 0; ks < 4; ks++) {
        sa0 = __builtin_amdgcn_mfma_f32_32x32x16_bf16(ak0[ks], bq[ks], sa0, 0, 0, 0);
        sa1 = __builtin_amdgcn_mfma_f32_32x32x16_bf16(ak1[ks], bq[ks], sa1, 0, 0, 0);
    }
    __builtin_amdgcn_s_setprio(0);
    if (domask) {
#pragma unroll
        for (int r = 0; r < 16; r++) {
            int crow = (r & 3) + 8 * (r >> 2) + 4 * hi8;
            if (kvb + crow > qg) sa0[r] = -1e30f;
            if (kvb + 32 + crow > qg) sa1[r] = -1e30f;
        }
    }
#pragma unroll
    for (int r = 0; r < 16; r++) sa0[r] = fast_exp2(sa0[r]);
#pragma unroll
    for (int r = 0; r < 16; r++) sa1[r] = fast_exp2(sa1[r]);

    unsigned a01 = cvt_pk_bf16(sa0[0], sa0[1]),  a23 = cvt_pk_bf16(sa0[2], sa0[3]);
    unsigned a45 = cvt_pk_bf16(sa0[4], sa0[5]),  a67 = cvt_pk_bf16(sa0[6], sa0[7]);
    asm("v_permlane32_swap_b32 %0, %1" : "+v"(a01), "+v"(a45));
    asm("v_permlane32_swap_b32 %0, %1" : "+v"(a23), "+v"(a67));
    unsigned b01 = cvt_pk_bf16(sa0[8], sa0[9]),  b23 = cvt_pk_bf16(sa0[10], sa0[11]);
    unsigned b45 = cvt_pk_bf16(sa0[12], sa0[13]), b67 = cvt_pk_bf16(sa0[14], sa0[15]);
    asm("v_permlane32_swap_b32 %0, %1" : "+v"(b01), "+v"(b45));
    asm("v_permlane32_swap_b32 %0, %1" : "+v"(b23), "+v"(b67));
    unsigned c01 = cvt_pk_bf16(sa1[0], sa1[1]),  c23 = cvt_pk_bf16(sa1[2], sa1[3]);
    unsigned c45 = cvt_pk_bf16(sa1[4], sa1[5]),  c67 = cvt_pk_bf16(sa1[6], sa1[7]);
    asm("v_permlane32_swap_b32 %0, %1" : "+v"(c01), "+v"(c45));
    asm("v_permlane32_swap_b32 %0, %1" : "+v"(c23), "+v"(c67));
    unsigned d01 = cvt_pk_bf16(sa1[8], sa1[9]),  d23 = cvt_pk_bf16(sa1[10], sa1[11]);
    unsigned d45 = cvt_pk_bf16(sa1[12], sa1[13]), d67 = cvt_pk_bf16(sa1[14], sa1[15]);
    asm("v_permlane32_swap_b32 %0, %1" : "+v"(d01), "+v"(d45));
    asm("v_permlane32_swap_b32 %0, %1" : "+v"(d23), "+v"(d67));
    union { unsigned u[4]; short8 s; } f0s0, f1s0, f0s1, f1s1;
    f0s0.u[0] = a01; f0s0.u[1] = a23; f0s0.u[2] = a45; f0s0.u[3] = a67;
    f1s0.u[0] = b01; f1s0.u[1] = b23; f1s0.u[2] = b45; f1s0.u[3] = b67;
    f0s1.u[0] = c01; f0s1.u[1] = c23; f0s1.u[2] = c45; f0s1.u[3] = c67;
    f1s1.u[0] = d01; f1s1.u[1] = d23; f1s1.u[2] = d45; f1s1.u[3] = d67;

    short8 bv00 = *reinterpret_cast<const short8*>(vbase + ql * 128 + (((0 + hi8) << 4) ^ sw4));
    short8 bv01 = *reinterpret_cast<const short8*>(vbase + ql * 128 + (((2 + hi8) << 4) ^ sw4));
    short8 bv02 = *reinterpret_cast<const short8*>(vbase + ql * 128 + (((4 + hi8) << 4) ^ sw4));
    short8 bv03 = *reinterpret_cast<const short8*>(vbase + ql * 128 + (((6 + hi8) << 4) ^ sw4));
    short8 bv10 = *reinterpret_cast<const short8*>(vbase + (32 + ql) * 128 + (((0 + hi8) << 4) ^ sw4));
    short8 bv11 = *reinterpret_cast<const short8*>(vbase + (32 + ql) * 128 + (((2 + hi8) << 4) ^ sw4));
    short8 bv12 = *reinterpret_cast<const short8*>(vbase + (32 + ql) * 128 + (((4 + hi8) << 4) ^ sw4));
    short8 bv13 = *reinterpret_cast<const short8*>(vbase + (32 + ql) * 128 + (((6 + hi8) << 4) ^ sw4));
    __builtin_amdgcn_s_setprio(1);
    st.lD = __builtin_amdgcn_mfma_f32_32x32x16_bf16(f0s0.s, ones1, st.lD, 0, 0, 0);
    st.lD = __builtin_amdgcn_mfma_f32_32x32x16_bf16(f1s0.s, ones1, st.lD, 0, 0, 0);
    st.lD = __builtin_amdgcn_mfma_f32_32x32x16_bf16(f0s1.s, ones1, st.lD, 0, 0, 0);
    st.lD = __builtin_amdgcn_mfma_f32_32x32x16_bf16(f1s1.s, ones1, st.lD, 0, 0, 0);
    st.o0 = __builtin_amdgcn_mfma_f32_32x32x16_bf16(f0s0.s, bv00, st.o0, 0, 0, 0);
    st.o1 = __builtin_amdgcn_mfma_f32_32x32x16_bf16(f0s0.s, bv10, st.o1, 0, 0, 0);
    st.o0 = __builtin_amdgcn_mfma_f32_32x32x16_bf16(f1s0.s, bv01, st.o0, 0, 0, 0);
    st.o1 = __builtin_amdgcn_mfma_f32_32x32x16_bf16(f1s0.s, bv11, st.o1, 0, 0, 0);
    st.o0 = __builtin_amdgcn_mfma_f32_32x32x16_bf16(f0s1.s, bv02, st.o0, 0, 0, 0);
    st.o1 = __builtin_amdgcn_mfma_f32_32x32x16_bf16(f0s1.s, bv12, st.o1, 0, 0, 0);
    st.o0 = __builtin_amdgcn_mfma_f32_32x32x16_bf16(f1s1.s, bv03, st.o0, 0, 0, 0);
    st.o1 = __builtin_amdgcn_mfma_f32_32x32x16_bf16(f1s1.s, bv13, st.o1, 0, 0, 0);
    __builtin_amdgcn_s_setprio(0);
}

__device__ __forceinline__ void attn_half_tile(
        const char* kbase, const char* vbase, const short8* bq, short8 ones1,
        AttnState& st, int sw4, int ql, int hi8, int sub, int kvb, int qg) {
    short8 ak[4];
#pragma unroll
    for (int ks = 0; ks < 4; ks++)
        ak[ks] = *reinterpret_cast<const short8*>(
            kbase + (sub * 32 + ql) * 128 + (((ks * 2 + hi8) << 4) ^ sw4));
    f32x16 sa = ZERO16;
#pragma unroll
    for (int ks = 0; ks < 4; ks++)
        sa = __builtin_amdgcn_mfma_f32_32x32x16_bf16(ak[ks], bq[ks], sa, 0, 0, 0);

#pragma unroll
    for (int r = 0; r < 16; r++) {
        int crow = (r & 3) + 8 * (r >> 2) + 4 * hi8;
        if (kvb + sub * 32 + crow > qg) sa[r] = -1e30f;
    }
#pragma unroll
    for (int r = 0; r < 16; r++) sa[r] = fast_exp2(sa[r]);

    unsigned a01 = cvt_pk_bf16(sa[0], sa[1]),  a23 = cvt_pk_bf16(sa[2], sa[3]);
    unsigned a45 = cvt_pk_bf16(sa[4], sa[5]),  a67 = cvt_pk_bf16(sa[6], sa[7]);
    asm("v_permlane32_swap_b32 %0, %1" : "+v"(a01), "+v"(a45));
    asm("v_permlane32_swap_b32 %0, %1" : "+v"(a23), "+v"(a67));
    unsigned b01 = cvt_pk_bf16(sa[8], sa[9]),  b23 = cvt_pk_bf16(sa[10], sa[11]);
    unsigned b45 = cvt_pk_bf16(sa[12], sa[13]), b67 = cvt_pk_bf16(sa[14], sa[15]);
    asm("v_permlane32_swap_b32 %0, %1" : "+v"(b01), "+v"(b45));
    asm("v_permlane32_swap_b32 %0, %1" : "+v"(b23), "+v"(b67));
    union { unsigned u[4]; short8 s; } f0, f1;
    f0.u[0] = a01; f0.u[1] = a23; f0.u[2] = a45; f0.u[3] = a67;
    f1.u[0] = b01; f1.u[1] = b23; f1.u[2] = b45; f1.u[3] = b67;

    st.lD = __builtin_amdgcn_mfma_f32_32x32x16_bf16(f0.s, ones1, st.lD, 0, 0, 0);
    st.lD = __builtin_amdgcn_mfma_f32_32x32x16_bf16(f1.s, ones1, st.lD, 0, 0, 0);

    short8 bv00 = *reinterpret_cast<const short8*>(vbase + ql * 128 + (((sub * 4 + 0 + hi8) << 4) ^ sw4));
    short8 bv01 = *reinterpret_cast<const short8*>(vbase + ql * 128 + (((sub * 4 + 2 + hi8) << 4) ^ sw4));
    short8 bv10 = *reinterpret_cast<const short8*>(vbase + (32 + ql) * 128 + (((sub * 4 + 0 + hi8) << 4) ^ sw4));
    short8 bv11 = *reinterpret_cast<const short8*>(vbase + (32 + ql) * 128 + (((sub * 4 + 2 + hi8) << 4) ^ sw4));
    st.o0 = __builtin_amdgcn_mfma_f32_32x32x16_bf16(f0.s, bv00, st.o0, 0, 0, 0);
    st.o1 = __builtin_amdgcn_mfma_f32_32x32x16_bf16(f0.s, bv10, st.o1, 0, 0, 0);
    st.o0 = __builtin_amdgcn_mfma_f32_32x32x16_bf16(f1.s, bv01, st.o0, 0, 0, 0);
    st.o1 = __builtin_amdgcn_mfma_f32_32x32x16_bf16(f1.s, bv11, st.o1, 0, 0, 0);
}

__global__ __launch_bounds__(256)
void attn_kernel(const unsigned short* __restrict__ qkv2,   // [B*T][2048] Q|K bf16
                 const unsigned short* __restrict__ vtg,    // [1024][B*T]  V^T bf16
                 unsigned short* __restrict__ outp) {
    __shared__ unsigned short Ks[4][64][64];   // 4-slot ring, XOR-swizzled rows
    __shared__ unsigned short Vt[4][64][64];

    const int b = blockIdx.z, h = blockIdx.x, p = blockIdx.y;
    const int qcl = p, qch = 31 - p;
    const int L = p + 1, Hn = 32 - p;
    const int NSTEP = 17;
    const int t = threadIdx.x;
    const int w = t >> 6, l = t & 63, ql = l & 31, hi8 = l >> 5;
    const int pr = w >> 1, rg = w & 1;
    const int q0h = qch * 64 + rg * 32;
    const int q0l = qcl * 64 + rg * 32;
    const int q0p = pr ? q0l : q0h;
    const unsigned short* base2 = qkv2 + (size_t)b * TT * QKW;

    short8 bq[4];
#pragma unroll
    for (int ks = 0; ks < 4; ks++)
        bq[ks] = *reinterpret_cast<const short8*>(
            &base2[(size_t)(q0p + ql) * QKW + h * 64 + ks * 16 + hi8 * 8]);

    AttnState st;
    st.o0 = ZERO16; st.o1 = ZERO16; st.lD = ZERO16;

    short8 ones1;
#pragma unroll
    for (int j = 0; j < 8; j++) ones1[j] = (short)0x3F80;

    const int krow = l >> 3;
    const int kc8 = (l & 7) ^ krow;
    const unsigned short* gk = &base2[(size_t)(w * 8 + krow) * QKW + DD + h * 64 + kc8 * 8];
    const unsigned short* gv = &vtg[(size_t)(h * 64 + w * 8 + krow) * MM + b * TT + kc8 * 8];

#define STAGE(TI) { \
    const int _s = (TI) & 3; \
    const size_t _kb = (size_t)(TI) * 64; \
    GLDS16(gk + _kb * QKW, &Ks[_s][w * 8][0]); \
    GLDS16(gk + (_kb + 32) * QKW, &Ks[_s][32 + w * 8][0]); \
    GLDS16(gv + _kb, &Vt[_s][w * 8][0]); \
    GLDS16(gv + (size_t)32 * MM + _kb, &Vt[_s][32 + w * 8][0]); }

#define WRITE_OUT(Q0) { \
    _Pragma("unroll") \
    for (int r = 0; r < 16; r++) { \
        int src = (r & 3) + 8 * (r >> 2) + 4 * hi8; \
        float inv = fast_rcp(st.lD[r]); \
        size_t off = (size_t)(b * TT + (Q0) + src) * DD + h * 64 + ql; \
        outp[off] = f2bf(st.o0[r] * inv); \
        outp[off + 32] = f2bf(st.o1[r] * inv); \
    } }

    STAGE(0);
    int nIss = 1;
    __syncthreads();

    const int sw4 = (ql & 7) << 4;
    for (int s = 0; s < NSTEP; s++) {
        // issue stages needed by step s+1
        {
            const int sn = s + 1;
            int lastN;
            if (sn < L) lastN = sn;
            else if (sn < NSTEP - 1) lastN = L + 2 * (sn - L) + 1;
            else if (sn == NSTEP - 1) lastN = Hn - 1;
            else lastN = -1;
            while (nIss <= lastN) { STAGE(nIss); nIss++; }
        }

        if (s == L && pr == 1) {
            WRITE_OUT(q0l);
            st.o0 = ZERO16; st.o1 = ZERO16; st.lD = ZERO16;
#pragma unroll
            for (int ks = 0; ks < 4; ks++)
                bq[ks] = *reinterpret_cast<const short8*>(
                    &base2[(size_t)(q0h + ql) * QKW + h * 64 + ks * 16 + hi8 * 8]);
        }

        if (s < L) {
            const int tile = s;
            const char* kbase = (const char*)&Ks[tile & 3][0][0];
            const char* vbase = (const char*)&Vt[tile & 3][0][0];
            const bool domask = (pr == 1) && (s == L - 1);
            attn_full_tile(kbase, vbase, bq, ones1, st, sw4, ql, hi8,
                           domask, tile * 64, q0p + ql);
        } else if (s < NSTEP - 1) {
            const int tile = L + 2 * (s - L) + pr;
            const char* kbase = (const char*)&Ks[tile & 3][0][0];
            const char* vbase = (const char*)&Vt[tile & 3][0][0];
            attn_full_tile(kbase, vbase, bq, ones1, st, sw4, ql, hi8,
                           false, 0, 0);
        } else {
            const int tile = Hn - 1;
            const char* kbase = (const char*)&Ks[tile & 3][0][0];
            const char* vbase = (const char*)&Vt[tile & 3][0][0];
            attn_half_tile(kbase, vbase, bq, ones1, st, sw4, ql, hi8,
                           pr, tile * 64, q0h + ql);
        }
        __syncthreads();
    }

    // merge pair-1 heavy partials into pair 0
    float* xf = (float*)&Ks[0][0][0];
    float* xl = (float*)&Vt[0][0][0];
    const int tid128 = (w & 1) * 64 + l;
    if (pr == 1) {
#pragma unroll
        for (int r = 0; r < 16; r++) {
            xf[r * 128 + tid128] = st.o0[r];
            xf[(16 + r) * 128 + tid128] = st.o1[r];
            xl[r * 128 + tid128] = st.lD[r];
        }
    }
    __syncthreads();
    if (pr == 0) {
#pragma unroll
        for (int r = 0; r < 16; r++) {
            st.o0[r] += xf[r * 128 + tid128];
            st.o1[r] += xf[(16 + r) * 128 + tid128];
            st.lD[r] += xl[r * 128 + tid128];
        }
        WRITE_OUT(q0h);
    }
#undef STAGE
#undef WRITE_OUT
}

extern "C" void kernel_launch(void* const* d_in, const int* in_sizes, int n_in,
                              void* d_out, int out_size, void* d_ws, size_t ws_size,
                              hipStream_t stream) {
    const float* x     = (const float*)d_in[0];   // [4096][1024]
    const float* Wqkv  = (const float*)d_in[1];   // [1024][3072]
    const float* Wproj = (const float*)d_in[2];   // [1024][1024]
    float* out = (float*)d_out;                    // [4096][1024] fp32

    unsigned short* xb     = (unsigned short*)d_ws;            // 4096*1024
    unsigned short* wqkvt  = xb + (size_t)MM * DD;             // 3072*1024
    unsigned short* wprojt = wqkvt + (size_t)N3 * DD;          // 1024*1024
    unsigned short* qkv2   = wprojt + (size_t)DD * DD;         // 4096*2048 (Q|K)
    unsigned short* vtg    = qkv2 + (size_t)MM * QKW;          // 1024*4096 (V^T)
    unsigned short* attout = vtg + (size_t)DD * MM;            // 4096*1024
    size_t need = ((size_t)MM * DD + (size_t)N3 * DD + (size_t)DD * DD +
                   (size_t)MM * QKW + (size_t)DD * MM + (size_t)MM * DD) * 2;
    if (ws_size < need) return;

    const float sc = 0.125f * 1.44269504088896f;   // 1/sqrt(64) * log2(e), folded into Q

    prep_kernel<<<5120, dim3(32, 8), 0, stream>>>(x, Wqkv, Wproj, xb, wqkvt, wprojt);

    gemm256_qkv<<<dim3(16, 16), 512, 0, stream>>>(xb, wqkvt, qkv2, vtg, sc);

    attn_kernel<<<dim3(HH, 16, BB), 256, 0, stream>>>(qkv2, vtg, attout);

    gemm_proj<<<dim3(16, 32), 256, 0, stream>>>(attout, wprojt, out);
}